// Round 4
// baseline (267.057 us; speedup 1.0000x reference)
//
#include <hip/hip_runtime.h>

// CQAttention: B=32, Lc=2048, Lq=256, d=128.
// out[b,i,:] = [C, C2Q, C*C2Q, C*Q2C], fp32, 512 wide.
//
// Pipeline (all bf16 MFMA 16x16x32), 5 dispatches:
//   memset: rq, l1 accumulators
//   prep : Qbf (row-major bf16), Qt (Q^T), Ct (C^T), rq = Q.w_q
//   k1   : E' = exp(S)/l2[i] (softmax axis-2) written BOTH row-major (E) and
//          transposed (ET, via in-register->LDS transpose); l2g; l1 atomics
//   k3   : Tt = Ct @ ET          (unscaled; pure vector staging both operands)
//   k4   : A2 = E'/l1 (scaled during staging);
//          C2Q = l2[i]*(A2@Qt), Q2C = l2[i]*(A2@Tt); fused epilogue
// Algebra: S1 = e/l1[j] = (E'/l1[j])*l2[i]  ->  scaling lives in A2 + epilogue.

#define LC 2048
#define LQ 256
#define DM 128
#define NEG_INF_F (-1e30f)

using bf16x8  = __attribute__((ext_vector_type(8))) __bf16;
using f32x4   = __attribute__((ext_vector_type(4))) float;
using ushort8 = __attribute__((ext_vector_type(8))) unsigned short;

__device__ __forceinline__ unsigned short f2bf(float x) {
    unsigned int u = __float_as_uint(x);
    u += 0x7fffu + ((u >> 16) & 1u);
    return (unsigned short)(u >> 16);
}
__device__ __forceinline__ float bf2f(unsigned short h) {
    return __uint_as_float(((unsigned int)h) << 16);
}
__device__ __forceinline__ f32x4 mfma16(bf16x8 a, bf16x8 b, f32x4 c) {
    return __builtin_amdgcn_mfma_f32_16x16x32_bf16(a, b, c, 0, 0, 0);
}

// ---------------------------------------------------------------------------
// prep: bx<8 -> Q part (Qbf row-major bf16, Qt transpose, rq atomics);
//       bx>=8 -> C transpose (Ct).
__global__ __launch_bounds__(256) void k_prep(const float* __restrict__ Q,
        const float* __restrict__ C, const float* __restrict__ w,
        unsigned short* __restrict__ Qbf, unsigned short* __restrict__ Qt,
        unsigned short* __restrict__ Ct, float* __restrict__ rq) {
    const int b = blockIdx.z, bx = blockIdx.x;
    const int tid = threadIdx.x;
    __shared__ float tile[64][65];
    __shared__ float wq[128];
    const int r = tid >> 2, c0 = (tid & 3) * 16;

    if (bx < 8) {
        const int j0 = (bx & 3) * 64, d0 = (bx >> 2) * 64;
        if (tid < 128) wq[tid] = w[tid];
        __syncthreads();
        const float4* sp = (const float4*)(Q + (size_t)(b * LQ + j0 + r) * DM + d0 + c0);
        float v[16];
#pragma unroll
        for (int u = 0; u < 4; ++u) {
            float4 t = sp[u];
            v[4*u] = t.x; v[4*u+1] = t.y; v[4*u+2] = t.z; v[4*u+3] = t.w;
        }
        unsigned short ob[16];
        float p = 0.f;
#pragma unroll
        for (int u = 0; u < 16; ++u) {
            ob[u] = f2bf(v[u]);
            p += v[u] * wq[d0 + c0 + u];
            tile[r][c0 + u] = v[u];
        }
        ushort8* qb = (ushort8*)(Qbf + (size_t)(b * LQ + j0 + r) * DM + d0 + c0);
        qb[0] = *(ushort8*)&ob[0];
        qb[1] = *(ushort8*)&ob[8];
        p += __shfl_xor(p, 1);
        p += __shfl_xor(p, 2);
        if ((tid & 3) == 0) atomicAdd(&rq[b * LQ + j0 + r], p);
        __syncthreads();
        unsigned short o[16];
#pragma unroll
        for (int u = 0; u < 16; ++u) o[u] = f2bf(tile[c0 + u][r]);
        ushort8* dp = (ushort8*)(Qt + (size_t)(b * DM + d0 + r) * LQ + j0 + c0);
        dp[0] = *(ushort8*)&o[0];
        dp[1] = *(ushort8*)&o[8];
    } else {
        const int x = bx - 8;
        const int i0 = (x >> 1) * 64, d0 = (x & 1) * 64;
        const float4* sp = (const float4*)(C + (size_t)(b * LC + i0 + r) * DM + d0 + c0);
#pragma unroll
        for (int u = 0; u < 4; ++u) {
            float4 t = sp[u];
            tile[r][c0 + 4*u] = t.x; tile[r][c0 + 4*u + 1] = t.y;
            tile[r][c0 + 4*u + 2] = t.z; tile[r][c0 + 4*u + 3] = t.w;
        }
        __syncthreads();
        unsigned short o[16];
#pragma unroll
        for (int u = 0; u < 16; ++u) o[u] = f2bf(tile[c0 + u][r]);
        ushort8* dp = (ushort8*)(Ct + (size_t)(b * DM + d0 + r) * LC + i0 + c0);
        dp[0] = *(ushort8*)&o[0];
        dp[1] = *(ushort8*)&o[8];
    }
}

// ---------------------------------------------------------------------------
// K1: E' = exp(S)/l2 -> E (row-major) and ET (transposed, vector-flushed).
// grid (32 itiles, 32 b), 256 thr, tile 64(i) x 256(j).
__global__ __launch_bounds__(256) void k1_scores(
    const float* __restrict__ C, const unsigned short* __restrict__ Qbf,
    const float* __restrict__ w, const float* __restrict__ bptr,
    const int* __restrict__ c_mask, const int* __restrict__ q_mask,
    const float* __restrict__ rq,
    unsigned short* __restrict__ E, unsigned short* __restrict__ ET,
    float* __restrict__ l1g, float* __restrict__ l2g) {
    const int b = blockIdx.y;
    const int i0 = blockIdx.x * 64;
    const int tid = threadIdx.x;
    const int lane = tid & 63, wid = tid >> 6;
    const int quad = lane >> 4, l15 = lane & 15;

    // union: Alds (64x136 = 17.4KB) lives during MFMA; ETl (256x72 = 36.9KB) after.
    __shared__ unsigned short ETl[256][72];
    unsigned short (*Alds)[136] = (unsigned short (*)[136])&ETl[0][0];
    __shared__ float wsm[256];                // [0:128)=w_c, [128:256)=w_m
    __shared__ float rcs[64], rqs[256], cms[64], qms[256], l2s[64];
    __shared__ float b0s;

    if (tid < 256) {
        wsm[tid] = w[128 + tid];
        rqs[tid] = rq[b * LQ + tid];
        qms[tid] = (float)q_mask[b * LQ + tid];
    }
    if (tid < 64) {
        cms[tid] = (float)c_mask[b * LC + i0 + tid];
        l2s[tid] = 0.f;
    }
    if (tid == 0) b0s = bptr[0];
    __syncthreads();

    {   // stage A = C*w_m (bf16), rc = C . w_c
        const int r = tid >> 2, qq = tid & 3;
        const float4* cp = (const float4*)(C + (size_t)(b * LC + i0 + r) * DM + qq * 32);
        float prc = 0.f;
#pragma unroll
        for (int u = 0; u < 8; ++u) {
            float4 v = cp[u];
            const int c0 = qq * 32 + u * 4;
            prc += v.x * wsm[c0] + v.y * wsm[c0 + 1] + v.z * wsm[c0 + 2] + v.w * wsm[c0 + 3];
            Alds[r][c0 + 0] = f2bf(v.x * wsm[128 + c0]);
            Alds[r][c0 + 1] = f2bf(v.y * wsm[129 + c0]);
            Alds[r][c0 + 2] = f2bf(v.z * wsm[130 + c0]);
            Alds[r][c0 + 3] = f2bf(v.w * wsm[131 + c0]);
        }
        prc += __shfl_xor(prc, 1);
        prc += __shfl_xor(prc, 2);
        if (qq == 0) rcs[r] = prc;
    }
    __syncthreads();

    const int n_base = wid * 64;
    const unsigned short* qbase = Qbf + (size_t)b * LQ * DM;
    const f32x4 z4 = {0.f, 0.f, 0.f, 0.f};
    f32x4 acc[4][4];
#pragma unroll
    for (int mt = 0; mt < 4; ++mt)
#pragma unroll
        for (int nt = 0; nt < 4; ++nt) acc[mt][nt] = z4;

#pragma unroll
    for (int kc = 0; kc < 4; ++kc) {
        const int ko = kc * 32 + quad * 8;
        bf16x8 af[4], bfr[4];
#pragma unroll
        for (int mt = 0; mt < 4; ++mt)
            af[mt] = *(const bf16x8*)&Alds[mt * 16 + l15][ko];
#pragma unroll
        for (int nt = 0; nt < 4; ++nt)
            bfr[nt] = *(const bf16x8*)(qbase + (size_t)(n_base + nt * 16 + l15) * DM + ko);
#pragma unroll
        for (int mt = 0; mt < 4; ++mt)
#pragma unroll
            for (int nt = 0; nt < 4; ++nt)
                acc[mt][nt] = mfma16(af[mt], bfr[nt], acc[mt][nt]);
    }

    const float b0 = b0s;
    float colsum[4] = {0.f, 0.f, 0.f, 0.f};
#pragma unroll
    for (int mt = 0; mt < 4; ++mt) {
#pragma unroll
        for (int reg = 0; reg < 4; ++reg) {
            const int m = mt * 16 + quad * 4 + reg;
            float rowsum = 0.f;
#pragma unroll
            for (int nt = 0; nt < 4; ++nt) {
                const int n = n_base + nt * 16 + l15;
                float s = acc[mt][nt][reg] + rcs[m] + rqs[n] + b0;
                const float mk = cms[m] * qms[n];
                s = s * mk + NEG_INF_F * (1.f - mk);
                const float e = __expf(s);
                acc[mt][nt][reg] = e;
                rowsum += e;
                colsum[nt] += e;
            }
            rowsum += __shfl_xor(rowsum, 1);
            rowsum += __shfl_xor(rowsum, 2);
            rowsum += __shfl_xor(rowsum, 4);
            rowsum += __shfl_xor(rowsum, 8);
            if (l15 == 0) atomicAdd(&l2s[m], rowsum);
        }
    }
#pragma unroll
    for (int nt = 0; nt < 4; ++nt) {
        float v = colsum[nt];
        v += __shfl_xor(v, 16);
        v += __shfl_xor(v, 32);
        if (quad == 0) atomicAdd(&l1g[b * LQ + n_base + nt * 16 + l15], v);
    }
    __syncthreads();   // l2s complete; all Alds reads done (union handoff)
    if (tid < 64) l2g[b * LC + i0 + tid] = l2s[tid];

    // E' = e/l2: row-major scalar global stores + transposed LDS tile.
#pragma unroll
    for (int mt = 0; mt < 4; ++mt) {
#pragma unroll
        for (int reg = 0; reg < 4; ++reg) {
            const int m = mt * 16 + quad * 4 + reg;
            const float rl = 1.0f / l2s[m];
            unsigned short* erow = E + (size_t)(b * LC + i0 + m) * LQ;
#pragma unroll
            for (int nt = 0; nt < 4; ++nt) {
                const int n = n_base + nt * 16 + l15;
                const unsigned short ev = f2bf(acc[mt][nt][reg] * rl);
                erow[n] = ev;
                ETl[n][m] = ev;
            }
        }
    }
    __syncthreads();

    // vector flush of ET: 2 rows per thread-pair round, 64B per thread per row.
    const int jr = tid >> 1, h = tid & 1;
#pragma unroll
    for (int rr = 0; rr < 2; ++rr) {
        const int j = jr + rr * 128;
        const unsigned short* lp = &ETl[j][h * 32];
        ushort8* gp = (ushort8*)(ET + (size_t)(b * LQ + j) * LC + i0 + h * 32);
#pragma unroll
        for (int u = 0; u < 4; ++u) gp[u] = *(const ushort8*)(lp + u * 8);
    }
}

// ---------------------------------------------------------------------------
// K3: Tt[d][j] = sum_i Ct[d][i]*ET[j][i] (unscaled). grid (4 jt, 2 dt, 32 b),
// 256 thr (4 waves, each 32x32), block tile 64x64, BK=128.
// Staging: 4 threads/row x 32 shorts (4 x ushort8) = 128 shorts per row.
__global__ __launch_bounds__(256) void k3_Tt(
    const unsigned short* __restrict__ ET, const unsigned short* __restrict__ Ct,
    unsigned short* __restrict__ Tt) {
    const int j0 = blockIdx.x * 64, d0 = blockIdx.y * 64, b = blockIdx.z;
    const int tid = threadIdx.x;
    const int lane = tid & 63, wid = tid >> 6;
    const int quad = lane >> 4, l15 = lane & 15;
    const int m32 = (wid & 1) * 32, n32 = (wid >> 1) * 32;

    __shared__ unsigned short Ab[64][136];   // Ct rows (d-major, i contiguous)
    __shared__ unsigned short Bb[64][136];   // ET rows (j-major, i contiguous)

    const f32x4 z4 = {0.f, 0.f, 0.f, 0.f};
    f32x4 acc[2][2] = {{z4, z4}, {z4, z4}};

    const int r = tid >> 2, q = tid & 3;
    for (int it = 0; it < 16; ++it) {
        const int ic = it * 128;
        __syncthreads();
        {
            const ushort8* cp = (const ushort8*)(Ct + (size_t)(b * DM + d0 + r) * LC + ic + q * 32);
            const ushort8* ep = (const ushort8*)(ET + (size_t)(b * LQ + j0 + r) * LC + ic + q * 32);
#pragma unroll
            for (int u = 0; u < 4; ++u) {
                *(ushort8*)&Ab[r][q * 32 + u * 8] = cp[u];
                *(ushort8*)&Bb[r][q * 32 + u * 8] = ep[u];
            }
        }
        __syncthreads();
#pragma unroll
        for (int kk = 0; kk < 4; ++kk) {
            const int ko = kk * 32 + quad * 8;
            bf16x8 a0 = *(const bf16x8*)&Ab[m32 + l15][ko];
            bf16x8 a1 = *(const bf16x8*)&Ab[m32 + 16 + l15][ko];
            bf16x8 b0 = *(const bf16x8*)&Bb[n32 + l15][ko];
            bf16x8 b1 = *(const bf16x8*)&Bb[n32 + 16 + l15][ko];
            acc[0][0] = mfma16(a0, b0, acc[0][0]);
            acc[0][1] = mfma16(a0, b1, acc[0][1]);
            acc[1][0] = mfma16(a1, b0, acc[1][0]);
            acc[1][1] = mfma16(a1, b1, acc[1][1]);
        }
    }
#pragma unroll
    for (int mt = 0; mt < 2; ++mt)
#pragma unroll
        for (int nt = 0; nt < 2; ++nt)
#pragma unroll
            for (int reg = 0; reg < 4; ++reg) {
                const int d = d0 + m32 + mt * 16 + quad * 4 + reg;
                const int j = j0 + n32 + nt * 16 + l15;
                Tt[(size_t)(b * DM + d) * LQ + j] = f2bf(acc[mt][nt][reg]);
            }
}

// ---------------------------------------------------------------------------
// K4: A2 = E'/l1 (scaled at staging); acc1 = A2@Qt, acc2 = A2@Tt;
// out = [C, l2*acc1, C*l2*acc1, C*l2*acc2]. grid (32 itiles, 32 b), 256 thr.
__global__ __launch_bounds__(256) void k4_out(
    const unsigned short* __restrict__ E, const float* __restrict__ C,
    const unsigned short* __restrict__ Qt, const unsigned short* __restrict__ Tt,
    const float* __restrict__ l1g, const float* __restrict__ l2g,
    float* __restrict__ out) {
    const int b = blockIdx.y;
    const int i0 = blockIdx.x * 64;
    const int tid = threadIdx.x;
    const int lane = tid & 63, wid = tid >> 6;
    const int quad = lane >> 4, l15 = lane & 15;
    const int n_base = wid * 32;

    __shared__ unsigned short Aq[64][72];    // A2 chunk [i][j]
    __shared__ unsigned short Bq[128][72];   // Qt chunk [d][j]
    __shared__ unsigned short Bt2[128][72];  // Tt chunk [d][j]
    __shared__ float rl1s[256];
    __shared__ float l2sm[64];
    rl1s[tid] = 1.0f / l1g[b * LQ + tid];
    if (tid < 64) l2sm[tid] = l2g[b * LC + i0 + tid];

    const f32x4 z4 = {0.f, 0.f, 0.f, 0.f};
    f32x4 acc1[4][2], acc2[4][2];
#pragma unroll
    for (int mt = 0; mt < 4; ++mt)
#pragma unroll
        for (int nt = 0; nt < 2; ++nt) { acc1[mt][nt] = z4; acc2[mt][nt] = z4; }

#pragma unroll 1
    for (int kc = 0; kc < 4; ++kc) {
        const int jc = kc * 64;
        __syncthreads();
        {   // A2: 64 rows x 64 shorts, 4 thr/row, scale by 1/l1[j]
            const int r = tid >> 2, q = tid & 3;
            const ushort8* ep = (const ushort8*)(E + (size_t)(b * LC + i0 + r) * LQ + jc + q * 16);
            ushort8 e0 = ep[0], e1 = ep[1];
            unsigned short o0[8], o1[8];
#pragma unroll
            for (int u = 0; u < 8; ++u) {
                o0[u] = f2bf(bf2f(e0[u]) * rl1s[jc + q * 16 + u]);
                o1[u] = f2bf(bf2f(e1[u]) * rl1s[jc + q * 16 + 8 + u]);
            }
            *(ushort8*)&Aq[r][q * 16] = *(ushort8*)&o0[0];
            *(ushort8*)&Aq[r][q * 16 + 8] = *(ushort8*)&o1[0];
        }
        {   // Bq/Bt2: 128 rows x 64 shorts, 2 thr/row
            const int r = tid >> 1, h = (tid & 1) * 32;
            const ushort8* qp = (const ushort8*)(Qt + (size_t)(b * DM + r) * LQ + jc + h);
            const ushort8* tp = (const ushort8*)(Tt + (size_t)(b * DM + r) * LQ + jc + h);
#pragma unroll
            for (int u = 0; u < 4; ++u) {
                *(ushort8*)&Bq[r][h + u * 8] = qp[u];
                *(ushort8*)&Bt2[r][h + u * 8] = tp[u];
            }
        }
        __syncthreads();
#pragma unroll
        for (int kk = 0; kk < 2; ++kk) {
            const int ko = kk * 32 + quad * 8;
            bf16x8 a[4], bq[2], bt[2];
#pragma unroll
            for (int mt = 0; mt < 4; ++mt)
                a[mt] = *(const bf16x8*)&Aq[mt * 16 + l15][ko];
#pragma unroll
            for (int nt = 0; nt < 2; ++nt) {
                bq[nt] = *(const bf16x8*)&Bq[n_base + nt * 16 + l15][ko];
                bt[nt] = *(const bf16x8*)&Bt2[n_base + nt * 16 + l15][ko];
            }
#pragma unroll
            for (int mt = 0; mt < 4; ++mt)
#pragma unroll
                for (int nt = 0; nt < 2; ++nt) {
                    acc1[mt][nt] = mfma16(a[mt], bq[nt], acc1[mt][nt]);
                    acc2[mt][nt] = mfma16(a[mt], bt[nt], acc2[mt][nt]);
                }
        }
    }

#pragma unroll
    for (int mt = 0; mt < 4; ++mt)
#pragma unroll
        for (int reg = 0; reg < 4; ++reg) {
            const int il = mt * 16 + quad * 4 + reg;
            const int i = i0 + il;
            const float l2v = l2sm[il];
            const size_t rb = (size_t)(b * LC + i) * 512;
            const float* crow = C + (size_t)(b * LC + i) * DM;
#pragma unroll
            for (int nt = 0; nt < 2; ++nt) {
                const int d = n_base + nt * 16 + l15;
                const float c = crow[d];
                const float v1 = acc1[mt][nt][reg] * l2v;
                const float v2 = acc2[mt][nt][reg] * l2v;
                out[rb + d] = c;
                out[rb + 128 + d] = v1;
                out[rb + 256 + d] = c * v1;
                out[rb + 384 + d] = c * v2;
            }
        }
}

// ---------------------------------------------------------------------------
extern "C" void kernel_launch(void* const* d_in, const int* in_sizes, int n_in,
                              void* d_out, int out_size, void* d_ws, size_t ws_size,
                              hipStream_t stream) {
    const float* C = (const float*)d_in[0];
    const float* Q = (const float*)d_in[1];
    const float* w = (const float*)d_in[2];
    const float* bp = (const float*)d_in[3];
    const int* cm = (const int*)d_in[4];
    const int* qm = (const int*)d_in[5];
    float* out = (float*)d_out;

    char* ws = (char*)d_ws;
    unsigned short* E   = (unsigned short*)(ws);
    unsigned short* ET  = (unsigned short*)(ws + 33554432);
    unsigned short* Ct  = (unsigned short*)(ws + 67108864);
    unsigned short* Qbf = (unsigned short*)(ws + 83886080);
    unsigned short* Qt  = (unsigned short*)(ws + 85983232);
    unsigned short* Tt  = (unsigned short*)(ws + 88080384);
    float*          l2g = (float*)(ws + 90177536);
    float*          rq  = (float*)(ws + 90439680);
    float*          l1  = (float*)(ws + 90472448);

    hipMemsetAsync(ws + 90439680, 0, 65536, stream);  // zero rq + l1

    k_prep<<<dim3(72, 1, 32), 256, 0, stream>>>(Q, C, w, Qbf, Qt, Ct, rq);
    k1_scores<<<dim3(32, 32), 256, 0, stream>>>(C, Qbf, w, bp, cm, qm, rq, E, ET, l1, l2g);
    k3_Tt<<<dim3(4, 2, 32), 256, 0, stream>>>(ET, Ct, Tt);
    k4_out<<<dim3(32, 32), 256, 0, stream>>>(E, C, Qt, Tt, l1, l2g, out);
}